// Round 22
// baseline (150.117 us; speedup 1.0000x reference)
//
#include <hip/hip_runtime.h>

// Problem constants: B=32, C_IN=64, C_OUT=128, K=3, H=W=128
#define BATCH 32
#define CIN   64
#define COUT  128
#define HW    128
#define OW    126            // H-K+1
#define IMG4  508032         // float4s per batch-image of out (128*126*126/4)

typedef float f4 __attribute__((ext_vector_type(4)));
typedef float f32x4 __attribute__((ext_vector_type(4)));
typedef short s8v __attribute__((ext_vector_type(8)));   // bf16x8 MFMA fragment
typedef unsigned short u16;

__device__ inline u16 bf16_rne(float v) {                // round-to-nearest-even
    unsigned b = __float_as_uint(v);
    unsigned r = b + 0x7FFF + ((b >> 16) & 1);
    return (u16)(r >> 16);
}
__device__ inline float bf16_f(u16 h) { return __uint_as_float(((unsigned)h) << 16); }

// ---- Kernel 1 (FROZEN, probed at read-roofline 21.3 us): batch-sum + pack ----
__global__ __launch_bounds__(256) void k_bsum(const float* __restrict__ x,
                                              const float* __restrict__ w,
                                              u16* __restrict__ xh,
                                              u16* __restrict__ xl,
                                              u16* __restrict__ wh,
                                              u16* __restrict__ wl) {
    __shared__ unsigned lds[128 * 17];            // packed (hi | lo<<16), pitch 17

    const int t     = threadIdx.x;
    const int hw0   = blockIdx.x * 128;
    const int cb    = blockIdx.y;                 // 0..3 -> ic0 = cb*16
    const int f4i   = t & 31;                     // f4 index over the 128-hw tile
    const int chalf = t >> 5;                     // 0..7

    const f4* __restrict__ x4 = (const f4*)x;
    const int rb = cb * 16 + chalf;               // first of 2 c-rows (other +8)
    const int hb = (hw0 >> 2) + f4i;              // f4 offset within a c-row

    f4 acc0 = {0.f, 0.f, 0.f, 0.f};
    f4 acc1 = {0.f, 0.f, 0.f, 0.f};
    #pragma unroll 4
    for (int b = 0; b < BATCH; ++b) {
        const size_t base = (size_t)b * 262144;
        acc0 += __builtin_nontemporal_load(&x4[base + (rb    ) * 4096 + hb]);
        acc1 += __builtin_nontemporal_load(&x4[base + (rb + 8) * 4096 + hb]);
    }

    #pragma unroll
    for (int j = 0; j < 4; ++j) {
        {
            const float v = acc0[j];
            const u16 h = bf16_rne(v);
            const u16 lo = bf16_rne(v - bf16_f(h));
            lds[(f4i * 4 + j) * 17 + chalf] = (unsigned)h | ((unsigned)lo << 16);
        }
        {
            const float v = acc1[j];
            const u16 h = bf16_rne(v);
            const u16 lo = bf16_rne(v - bf16_f(h));
            lds[(f4i * 4 + j) * 17 + chalf + 8] = (unsigned)h | ((unsigned)lo << 16);
        }
    }
    __syncthreads();

    unsigned* __restrict__ xhu = (unsigned*)xh;
    unsigned* __restrict__ xlu = (unsigned*)xl;
    const int base = cb * 131072 + hw0 * 8;       // u32 index: tile 16384*16/2 per cb
    #pragma unroll
    for (int k = 0; k < 4; ++k) {
        const int l  = t * 4 + k;                 // 0..1023
        const int hw = l >> 3;
        const int wi = l & 7;
        const unsigned e0 = lds[hw * 17 + 2 * wi];
        const unsigned e1 = lds[hw * 17 + 2 * wi + 1];
        xhu[base + l] = (e0 & 0xFFFFu) | (e1 << 16);
        xlu[base + l] = (e0 >> 16) | (e1 & 0xFFFF0000u);
    }

    // Weight repack+split: idx = (t*128+oc)*64+ic <- w[(oc*64+ic)*9 + t]
    const int bid = blockIdx.y * 128 + blockIdx.x;
    if (bid < 288) {
        const int idx = bid * 256 + t;            // 0..73727
        const int ic = idx & 63;
        const int oc = (idx >> 6) & 127;
        const int tp = idx >> 13;
        const float v = w[(oc * 64 + ic) * 9 + tp];
        const u16 h = bf16_rne(v);
        wh[idx] = h;
        wl[idx] = bf16_rne(v - bf16_f(h));
    }
}

// ---- Kernel 2: MEASUREMENT ROUND — R21 conv body replayed 8x in-kernel ----
// Pointer-laundering defeats load CSE across reps (each rep = faithful replay);
// keepalives prevent DCE of reps 0..6; only the last rep's acc is stored, so
// output is identical to R21. Purpose: crack the top-5 and get conv counters.
__global__ __launch_bounds__(256) void k_conv(const u16* __restrict__ xh,
                                              const u16* __restrict__ wh,
                                              const float* __restrict__ bias,
                                              float* __restrict__ out) {
    const int tid  = threadIdx.x;
    const int l    = tid & 63;
    const int ocb  = (tid >> 6) * 32;       // wave -> 32 output channels
    const int row  = blockIdx.x;            // 0..125
    const int col0 = blockIdx.y * 32;       // 0,32,64,96
    const int n = l & 15;
    const int g = l >> 4;

    f32x4 acc[2][2];

    const u16* xp = xh;
    const u16* wp = wh;

    #pragma unroll 1
    for (int rep = 0; rep < 8; ++rep) {
        asm volatile("" : "+v"(xp), "+v"(wp));   // launder: loads can't CSE across reps
        acc[0][0] = (f32x4){0.f, 0.f, 0.f, 0.f};
        acc[0][1] = (f32x4){0.f, 0.f, 0.f, 0.f};
        acc[1][0] = (f32x4){0.f, 0.f, 0.f, 0.f};
        acc[1][1] = (f32x4){0.f, 0.f, 0.f, 0.f};

        #pragma unroll
        for (int kb = 0; kb < 2; ++kb) {
            const int icoff = kb * 32 + g * 8;
            const size_t tb = (size_t)(kb * 2 + (g >> 1)) * 262144;  // tile base (u16)
            const int off = (g & 1) * 8;
            #pragma unroll
            for (int t = 0; t < 9; ++t) {
                const int ky = t / 3, kx = t % 3;
                const int r  = row + ky;                         // <= 127, in-bounds
                const int c0 = min(col0 + kx + n, 127);          // clamp: junk masked on store
                const int c1 = min(col0 + kx + 16 + n, 127);
                const s8v bh0 = *(const s8v*)(xp + tb + (r * 128 + c0) * 16 + off);
                const s8v bh1 = *(const s8v*)(xp + tb + (r * 128 + c1) * 16 + off);
                const int wb0 = (t * 128 + ocb + n) * 64 + icoff;
                const s8v ah0 = *(const s8v*)(wp + wb0);
                const s8v ah1 = *(const s8v*)(wp + wb0 + 16 * 64);
                acc[0][0] = __builtin_amdgcn_mfma_f32_16x16x32_bf16(ah0, bh0, acc[0][0], 0, 0, 0);
                acc[0][1] = __builtin_amdgcn_mfma_f32_16x16x32_bf16(ah0, bh1, acc[0][1], 0, 0, 0);
                acc[1][0] = __builtin_amdgcn_mfma_f32_16x16x32_bf16(ah1, bh0, acc[1][0], 0, 0, 0);
                acc[1][1] = __builtin_amdgcn_mfma_f32_16x16x32_bf16(ah1, bh1, acc[1][1], 0, 0, 0);
            }
        }
        // keep this rep's results live (prevents DCE of reps 0..6)
        asm volatile("" :: "v"(acc[0][0]), "v"(acc[0][1]), "v"(acc[1][0]), "v"(acc[1][1]));
    }

    #pragma unroll
    for (int om = 0; om < 2; ++om) {
        #pragma unroll
        for (int j = 0; j < 4; ++j) {
            const int oc = ocb + om * 16 + g * 4 + j;
            const float bv = bias[oc];
            #pragma unroll
            for (int on = 0; on < 2; ++on) {
                const int col = col0 + on * 16 + n;
                if (col < OW)
                    out[((size_t)oc * OW + row) * OW + col] = acc[om][on][j] + bv;
            }
        }
    }
}

// ---- Kernel 3 (FROZEN, probed at write-roofline 38 us): fan-out broadcast ----
__global__ __launch_bounds__(256) void k_bcast(float* __restrict__ out) {
    f4* __restrict__ o4 = (f4*)out;
    const int r0 = blockIdx.x * 512 + threadIdx.x;
    const int r1 = r0 + 256;
    const bool ok0 = r0 < IMG4;
    const bool ok1 = r1 < IMG4;
    f4 v0 = {}; f4 v1 = {};
    if (ok0) v0 = o4[r0];
    if (ok1) v1 = o4[r1];
    #pragma unroll
    for (int b = 1; b < BATCH; ++b) {
        const size_t base = (size_t)b * IMG4;
        if (ok0) o4[base + r0] = v0;
        if (ok1) o4[base + r1] = v1;
    }
}

extern "C" void kernel_launch(void* const* d_in, const int* in_sizes, int n_in,
                              void* d_out, int out_size, void* d_ws, size_t ws_size,
                              hipStream_t stream) {
    const float* x    = (const float*)d_in[0];   // [32,64,128,128]
    const float* w    = (const float*)d_in[1];   // [128,64,3,3]
    const float* bias = (const float*)d_in[2];   // [128,1,1]
    float* out = (float*)d_out;                  // [32,128,126,126]

    u16* xh = (u16*)d_ws;                        // 1,048,576 elems (2 MB)
    u16* xl = xh + 1048576;                      // 2 MB (written, unused by conv)
    u16* wh = xl + 1048576;                      // 73,728 elems (144 KB)
    u16* wl = wh + 73728;                        // 144 KB (written, unused by conv)

    k_bsum<<<dim3(128, 4), dim3(256), 0, stream>>>(x, w, xh, xl, wh, wl);
    k_conv<<<dim3(OW, 4), dim3(256), 0, stream>>>(xh, wh, bias, out);
    k_bcast<<<dim3((IMG4 + 511) / 512), dim3(256), 0, stream>>>(out);
}

// Round 23
// 80.883 us; speedup vs baseline: 1.8560x; 1.8560x over previous
//
#include <hip/hip_runtime.h>

// Problem constants: B=32, C_IN=64, C_OUT=128, K=3, H=W=128
#define BATCH 32
#define CIN   64
#define COUT  128
#define HW    128
#define OW    126            // H-K+1
#define IMG4  508032         // float4s per batch-image of out (128*126*126/4)

typedef float f4 __attribute__((ext_vector_type(4)));
typedef float f32x4 __attribute__((ext_vector_type(4)));
typedef short s8v __attribute__((ext_vector_type(8)));   // bf16x8 MFMA fragment
typedef unsigned short u16;

__device__ inline u16 bf16_rne(float v) {                // round-to-nearest-even
    unsigned b = __float_as_uint(v);
    unsigned r = b + 0x7FFF + ((b >> 16) & 1);
    return (u16)(r >> 16);
}
__device__ inline float bf16_f(u16 h) { return __uint_as_float(((unsigned)h) << 16); }

// ---- Kernel 1 (FROZEN, probed at read-roofline 21.3 us): batch-sum + pack ----
__global__ __launch_bounds__(256) void k_bsum(const float* __restrict__ x,
                                              const float* __restrict__ w,
                                              u16* __restrict__ xh,
                                              u16* __restrict__ xl,
                                              u16* __restrict__ wh,
                                              u16* __restrict__ wl) {
    __shared__ unsigned lds[128 * 17];            // packed (hi | lo<<16), pitch 17

    const int t     = threadIdx.x;
    const int hw0   = blockIdx.x * 128;
    const int cb    = blockIdx.y;                 // 0..3 -> ic0 = cb*16
    const int f4i   = t & 31;                     // f4 index over the 128-hw tile
    const int chalf = t >> 5;                     // 0..7

    const f4* __restrict__ x4 = (const f4*)x;
    const int rb = cb * 16 + chalf;               // first of 2 c-rows (other +8)
    const int hb = (hw0 >> 2) + f4i;              // f4 offset within a c-row

    f4 acc0 = {0.f, 0.f, 0.f, 0.f};
    f4 acc1 = {0.f, 0.f, 0.f, 0.f};
    #pragma unroll 4
    for (int b = 0; b < BATCH; ++b) {
        const size_t base = (size_t)b * 262144;
        acc0 += __builtin_nontemporal_load(&x4[base + (rb    ) * 4096 + hb]);
        acc1 += __builtin_nontemporal_load(&x4[base + (rb + 8) * 4096 + hb]);
    }

    #pragma unroll
    for (int j = 0; j < 4; ++j) {
        {
            const float v = acc0[j];
            const u16 h = bf16_rne(v);
            const u16 lo = bf16_rne(v - bf16_f(h));
            lds[(f4i * 4 + j) * 17 + chalf] = (unsigned)h | ((unsigned)lo << 16);
        }
        {
            const float v = acc1[j];
            const u16 h = bf16_rne(v);
            const u16 lo = bf16_rne(v - bf16_f(h));
            lds[(f4i * 4 + j) * 17 + chalf + 8] = (unsigned)h | ((unsigned)lo << 16);
        }
    }
    __syncthreads();

    unsigned* __restrict__ xhu = (unsigned*)xh;
    unsigned* __restrict__ xlu = (unsigned*)xl;
    const int base = cb * 131072 + hw0 * 8;       // u32 index: tile 16384*16/2 per cb
    #pragma unroll
    for (int k = 0; k < 4; ++k) {
        const int l  = t * 4 + k;                 // 0..1023
        const int hw = l >> 3;
        const int wi = l & 7;
        const unsigned e0 = lds[hw * 17 + 2 * wi];
        const unsigned e1 = lds[hw * 17 + 2 * wi + 1];
        xhu[base + l] = (e0 & 0xFFFFu) | (e1 << 16);
        xlu[base + l] = (e0 >> 16) | (e1 & 0xFFFF0000u);
    }

    // Weight repack+split: idx = (t*128+oc)*64+ic <- w[(oc*64+ic)*9 + t]
    const int bid = blockIdx.y * 128 + blockIdx.x;
    if (bid < 288) {
        const int idx = bid * 256 + t;            // 0..73727
        const int ic = idx & 63;
        const int oc = (idx >> 6) & 127;
        const int tp = idx >> 13;
        const float v = w[(oc * 64 + ic) * 9 + tp];
        const u16 h = bf16_rne(v);
        wh[idx] = h;
        wl[idx] = bf16_rne(v - bf16_f(h));
    }
}

// ---- Kernel 2 (lever: LDS B-stage, XOR-swizzled): bf16 MFMA conv ----
// R21 geometry. The block's B-tile (3 rows x 34 cols x 64 ic = 13 KB) is
// staged ONCE in LDS (coalesced 2KB runs, 1 barrier); waves read fragments
// via ds_read_b128. Kills the 4-wave x kx-overlap B-load redundancy:
// VMEM/thread 72 -> 40. Swizzle: 16B slot ^= (cc&7) (128B rows would be
// 16-way bank conflict; swizzled = 2-way = free, m136).
__global__ __launch_bounds__(256) void k_conv(const u16* __restrict__ xh,
                                              const u16* __restrict__ wh,
                                              const float* __restrict__ bias,
                                              float* __restrict__ out) {
    __shared__ u16 lx[3 * 34 * 64];          // [rr][cc][64ic], swizzled: 13 KB

    const int tid  = threadIdx.x;
    const int l    = tid & 63;
    const int ocb  = (tid >> 6) * 32;        // wave -> 32 output channels
    const int row  = blockIdx.x;             // 0..125
    const int col0 = blockIdx.y * 32;        // 0,32,64,96
    const int n = l & 15;
    const int g = l >> 4;

    // ---- Stage B-tile: 816 16B-granules, coalesced (2KB runs per (cb,rr)) ----
    // q2 = ((cb*3 + rr)*34 + cc)*2 + h16 ; src u16 = cb*262144 + (r*128+c)*16 + h16*8
    // dst u16 = (rr*34+cc)*64 + ((cb*2+h16)*8 ^ ((cc&7)<<3))
    #pragma unroll
    for (int q = 0; q < 4; ++q) {
        const int q2 = tid + q * 256;
        if (q2 < 816) {
            const int h16  = q2 & 1;
            const int tmp  = q2 >> 1;
            const int cc   = tmp % 34;
            const int tmp2 = tmp / 34;
            const int rr   = tmp2 % 3;
            const int cb   = tmp2 / 3;
            const int c    = min(col0 + cc, 127);
            const s8v v = *(const s8v*)(xh + (size_t)cb * 262144
                                           + ((row + rr) * 128 + c) * 16 + h16 * 8);
            *(s8v*)(lx + (rr * 34 + cc) * 64 + (((cb * 2 + h16) * 8) ^ ((cc & 7) << 3))) = v;
        }
    }
    __syncthreads();                          // the only barrier

    f32x4 acc[2][2] = {};                     // [om][on]

    #pragma unroll
    for (int kb = 0; kb < 2; ++kb) {
        const int icoff = kb * 32 + g * 8;
        const int slot8 = (kb * 4 + g) * 8;   // u16 offset of this g's 16B slot
        #pragma unroll
        for (int t = 0; t < 9; ++t) {
            const int ky = t / 3, kx = t % 3;
            const int cc0 = kx + n;                          // on=0 pixel col offset
            const int cc1 = kx + n + 16;                     // on=1
            const s8v bh0 = *(const s8v*)(lx + (ky * 34 + cc0) * 64 + (slot8 ^ ((cc0 & 7) << 3)));
            const s8v bh1 = *(const s8v*)(lx + (ky * 34 + cc1) * 64 + (slot8 ^ ((cc1 & 7) << 3)));
            const int wb0 = (t * 128 + ocb + n) * 64 + icoff;
            const s8v ah0 = *(const s8v*)(wh + wb0);
            const s8v ah1 = *(const s8v*)(wh + wb0 + 16 * 64);
            acc[0][0] = __builtin_amdgcn_mfma_f32_16x16x32_bf16(ah0, bh0, acc[0][0], 0, 0, 0);
            acc[0][1] = __builtin_amdgcn_mfma_f32_16x16x32_bf16(ah0, bh1, acc[0][1], 0, 0, 0);
            acc[1][0] = __builtin_amdgcn_mfma_f32_16x16x32_bf16(ah1, bh0, acc[1][0], 0, 0, 0);
            acc[1][1] = __builtin_amdgcn_mfma_f32_16x16x32_bf16(ah1, bh1, acc[1][1], 0, 0, 0);
        }
    }

    #pragma unroll
    for (int om = 0; om < 2; ++om) {
        #pragma unroll
        for (int j = 0; j < 4; ++j) {
            const int oc = ocb + om * 16 + g * 4 + j;
            const float bv = bias[oc];
            #pragma unroll
            for (int on = 0; on < 2; ++on) {
                const int col = col0 + on * 16 + n;
                if (col < OW)
                    out[((size_t)oc * OW + row) * OW + col] = acc[om][on][j] + bv;
            }
        }
    }
}

// ---- Kernel 3 (FROZEN, probed at write-roofline 38 us): fan-out broadcast ----
__global__ __launch_bounds__(256) void k_bcast(float* __restrict__ out) {
    f4* __restrict__ o4 = (f4*)out;
    const int r0 = blockIdx.x * 512 + threadIdx.x;
    const int r1 = r0 + 256;
    const bool ok0 = r0 < IMG4;
    const bool ok1 = r1 < IMG4;
    f4 v0 = {}; f4 v1 = {};
    if (ok0) v0 = o4[r0];
    if (ok1) v1 = o4[r1];
    #pragma unroll
    for (int b = 1; b < BATCH; ++b) {
        const size_t base = (size_t)b * IMG4;
        if (ok0) o4[base + r0] = v0;
        if (ok1) o4[base + r1] = v1;
    }
}

extern "C" void kernel_launch(void* const* d_in, const int* in_sizes, int n_in,
                              void* d_out, int out_size, void* d_ws, size_t ws_size,
                              hipStream_t stream) {
    const float* x    = (const float*)d_in[0];   // [32,64,128,128]
    const float* w    = (const float*)d_in[1];   // [128,64,3,3]
    const float* bias = (const float*)d_in[2];   // [128,1,1]
    float* out = (float*)d_out;                  // [32,128,126,126]

    u16* xh = (u16*)d_ws;                        // 1,048,576 elems (2 MB)
    u16* xl = xh + 1048576;                      // 2 MB (written, unused by conv)
    u16* wh = xl + 1048576;                      // 73,728 elems (144 KB)
    u16* wl = wh + 73728;                        // 144 KB (written, unused by conv)

    k_bsum<<<dim3(128, 4), dim3(256), 0, stream>>>(x, w, xh, xl, wh, wl);
    k_conv<<<dim3(OW, 4), dim3(256), 0, stream>>>(xh, wh, bias, out);
    k_bcast<<<dim3((IMG4 + 511) / 512), dim3(256), 0, stream>>>(out);
}